// Round 2
// baseline (375.221 us; speedup 1.0000x reference)
//
#include <hip/hip_runtime.h>
#include <hip/hip_fp16.h>
#include <hip/hip_bf16.h>

#define BATCH   256
#define DIMS    64
#define LEVELS  100
#define HVD     10000
#define WH      32        // h-tile columns per block
#define NHT     313       // ceil(HVD/WH); tile 312 has 16 valid cols
#define DSPLIT  4
#define DPER    16
#define TPB     256       // 4 waves
#define FTPB    1024      // finish: 16 waves -> 4 waves/SIMD of TLP
#define CHUNK_FLOATS (LEVELS * WH)            // 3200 floats = 12.8 KB
#define NSTG    13        // staging instrs per chunk (8 rows/instr; p=12 half-masked)

typedef unsigned int   uint;
typedef unsigned short ushort;

// d_ws layout: [0, 20.48 MB) bf16 partial [DSPLIT][BATCH][HVD]

static __device__ __forceinline__ ushort f2bf(float f) {
    __hip_bfloat16 h = __float2bfloat16(f);   // RNE
    return *reinterpret_cast<ushort*>(&h);
}

// ---------------------------------------------------------------------------
// Encode: block = (h-tile 32 cols, d-split of 16 dims) x ALL 256 batches.
// NEVER-DRAIN K-loop: double-buffered LDS chunks staged via global_load_lds,
// raw s_barrier + manual s_waitcnt vmcnt(N) so the next chunk's loads stay
// in flight through every compute phase (HBM duty cycle ~100%).
// Chunk = 100 rows x 32 floats = 12.8 KB, staged by 13 instrs of
// 8 rows/instr (srow = lane>>3, scol = (lane&7)*4; p=12 masks rows >= 100).
// Per wave, loads/chunk = 4 (wave 0) or 3 (waves 1-3); waiting vmcnt(3)
// completes the current chunk for all waves (wave 0 over-waits by 1 load).
// The K-loop issues NO other vmcnt ops (params computed in the prologue and
// fully drained by the __syncthreads below), so the manual counts are exact.
// Each base byte fetched once, coalesced (8 x 128 B segments per instr).
//
// SETUP IS FUSED: thread tid owns batch b=tid; its 16 dims d0..d0+15 are
// contiguous in x -> four float4 loads, pack fp16(alpha)|lo<<16|hi<<24 into
// s_prm. x is 64 KB -> L2/L3-resident broadcast across blocks.
//
// LDS = 25.6 KB chunks + 16 KB prm = 41.6 KB -> 3 blocks/CU.
// ---------------------------------------------------------------------------
__global__ __launch_bounds__(TPB, 3) void encode_kernel(
    const float* __restrict__ x,
    const float* __restrict__ base,
    ushort*     __restrict__ partial)      // bf16 [DSPLIT][BATCH][HVD]
{
    __shared__ float s_buf[2][CHUNK_FLOATS];   // 25.6 KB
    __shared__ uint  s_prm[DPER][BATCH];       // 16 KB

    const int tid   = threadIdx.x;
    const int w     = tid >> 6;            // wave 0..3
    const int lane  = tid & 63;
    const int htile = blockIdx.x;
    const int split = blockIdx.y;
    const int h0    = htile * WH;
    const int d0    = split * DPER;
    const int wvalid = (HVD - h0) < WH ? (HVD - h0) : WH;

    // Fused param setup (b = tid, d = d0 + k). Drained by the __syncthreads
    // below, so these loads never pollute the K-loop's vmcnt bookkeeping.
    {
        const float4* xr = (const float4*)(x + (size_t)tid * DIMS + d0);
        const float4 x0 = xr[0];
        const float4 x1 = xr[1];
        const float4 x2 = xr[2];
        const float4 x3 = xr[3];
        const float xv[16] = { x0.x, x0.y, x0.z, x0.w, x1.x, x1.y, x1.z, x1.w,
                               x2.x, x2.y, x2.z, x2.w, x3.x, x3.y, x3.z, x3.w };
        #pragma unroll
        for (int k = 0; k < DPER; ++k) {
            float xn = fminf(fmaxf(xv[k] * (float)(LEVELS - 1), 0.0f),
                             (float)(LEVELS - 1));
            float fl = floorf(xn);
            int   lo = (int)fl;
            int   hi = lo < LEVELS - 1 ? lo + 1 : LEVELS - 1;
            uint abits = (uint)__half_as_ushort(__float2half(xn - fl));
            s_prm[k][tid] = abits | ((uint)lo << 16) | ((uint)hi << 24);
        }
    }
    __syncthreads();   // params visible; all counters drained

    const int srow = lane >> 3;            // staging: row within 8-row group
    const int scol = (lane & 7) * 4;       // staging: float col
    const float* srcdim = base + (size_t)d0 * LEVELS * HVD + h0;

    auto issue_chunk = [&](int dc, int bufidx) {
        const float* src = srcdim + (size_t)dc * LEVELS * HVD;
        float* dst = &s_buf[bufidx][0];
        for (int p = w; p < NSTG; p += 4) {          // wave0:4, waves1-3:3
            const int row = 8 * p + srow;
            const float* g = src + (size_t)row * HVD + scol;
            if (row < LEVELS && scol < wvalid) {     // lane mask; instr still issues
                __builtin_amdgcn_global_load_lds(
                    (const __attribute__((address_space(1))) uint*)g,
                    (__attribute__((address_space(3))) uint*)(dst + p * 8 * WH),
                    16, 0, 0);
            }
        }
    };

    issue_chunk(0, 0);
    issue_chunk(1, 1);

    const int sub   = lane >> 4;           // batch sub 0..3
    const int p2    = lane & 15;           // col pair (2 floats) within 32 cols
    const int pb    = p2 * 8;              // byte offset within a 128 B row
    const int bbase = w * 64;              // this wave's 64 batches

    float2 acc[16];
    #pragma unroll
    for (int j = 0; j < 16; ++j) acc[j] = make_float2(0.f, 0.f);

    #pragma unroll 1
    for (int dc = 0; dc < DPER; ++dc) {
        // Wait for chunk dc only; chunk dc+1's loads remain in flight.
        if (dc < DPER - 1) asm volatile("s_waitcnt vmcnt(3)" ::: "memory");
        else               asm volatile("s_waitcnt vmcnt(0)" ::: "memory");
        __builtin_amdgcn_s_barrier();      // all waves' chunk-dc portions landed

        const char* buf = (const char*)&s_buf[dc & 1][0];
        #pragma unroll
        for (int j = 0; j < 16; ++j) {
            // b128 broadcast of 4 consecutive batches' params; static select
            const uint4 pp = *(const uint4*)&s_prm[dc][bbase + 4 * j];
            const uint pk = (sub & 2) ? ((sub & 1) ? pp.w : pp.z)
                                      : ((sub & 1) ? pp.y : pp.x);
            const float a = __half2float(__ushort_as_half((ushort)(pk & 0xffffu)));
            const int olo = (int)((pk >> 16) & 0xffu) << 7;   // lo * 128 B
            const int ohi = (int)(pk >> 24) << 7;             // hi * 128 B
            const float2 vlo = *(const float2*)(buf + olo + pb);
            const float2 vhi = *(const float2*)(buf + ohi + pb);
            const float wl = 1.0f - a;
            acc[j].x += wl * vlo.x + a * vhi.x;
            acc[j].y += wl * vlo.y + a * vhi.y;
        }
        asm volatile("" ::: "memory");     // pin reads before the reuse barrier
        __builtin_amdgcn_s_barrier();      // all waves done reading buf[dc&1]
        if (dc < DPER - 2) issue_chunk(dc + 2, dc & 1);   // overwrite freed buffer
    }

    // bf16 partial store: per 16-lane group, one batch row x 64 B contiguous.
    if (p2 * 2 < wvalid) {
        #pragma unroll
        for (int j = 0; j < 16; ++j) {
            const int b = bbase + 4 * j + sub;
            const uint pk = (uint)f2bf(acc[j].x) | ((uint)f2bf(acc[j].y) << 16);
            *(uint*)(partial + ((size_t)split * BATCH + b) * (size_t)HVD + h0 + p2 * 2) = pk;
        }
    }
}

// ---------------------------------------------------------------------------
// Finish: SINGLE-PASS. Per batch row: sum the 4 bf16 partials into registers
// (<=16 floats/thread), block-reduce sum-of-squares, scale in-register,
// store out exactly once. 16 B uint4 loads: 8 bf16 per load per sp-stream.
// ---------------------------------------------------------------------------
__global__ __launch_bounds__(FTPB) void finish_kernel(
    const ushort* __restrict__ partial,    // bf16 [DSPLIT][BATCH][HVD]
    float* __restrict__ out)               // fp32 [BATCH][HVD]
{
    const int b   = blockIdx.x;
    const int tid = threadIdx.x;

    // HVD/8 = 1250 groups of 8 floats; k=0: g=tid, k=1: g=tid+1024 (<1250)
    float4 v0[2], v1[2];
    float  ss = 0.f;
    #pragma unroll
    for (int k = 0; k < 2; ++k) {
        const int g = k * FTPB + tid;
        float4 a = make_float4(0.f, 0.f, 0.f, 0.f);
        float4 c = make_float4(0.f, 0.f, 0.f, 0.f);
        if (g < HVD / 8) {
            #pragma unroll
            for (int sp = 0; sp < DSPLIT; ++sp) {
                const uint4 u = *(const uint4*)(partial +
                    ((size_t)sp * BATCH + b) * (size_t)HVD + (size_t)g * 8);
                a.x += __uint_as_float(u.x << 16);
                a.y += __uint_as_float(u.x & 0xffff0000u);
                a.z += __uint_as_float(u.y << 16);
                a.w += __uint_as_float(u.y & 0xffff0000u);
                c.x += __uint_as_float(u.z << 16);
                c.y += __uint_as_float(u.z & 0xffff0000u);
                c.z += __uint_as_float(u.w << 16);
                c.w += __uint_as_float(u.w & 0xffff0000u);
            }
            ss += a.x * a.x + a.y * a.y + a.z * a.z + a.w * a.w
                + c.x * c.x + c.y * c.y + c.z * c.z + c.w * c.w;
        }
        v0[k] = a; v1[k] = c;
    }

    __shared__ float red[FTPB];
    red[tid] = ss;
    __syncthreads();
    #pragma unroll
    for (int sh = FTPB / 2; sh > 0; sh >>= 1) {
        if (tid < sh) red[tid] += red[tid + sh];
        __syncthreads();
    }
    const float inv = rsqrtf(red[0]);

    #pragma unroll
    for (int k = 0; k < 2; ++k) {
        const int g = k * FTPB + tid;
        if (g < HVD / 8) {
            float4 a = v0[k], c = v1[k];
            a.x *= inv; a.y *= inv; a.z *= inv; a.w *= inv;
            c.x *= inv; c.y *= inv; c.z *= inv; c.w *= inv;
            *(float4*)(out + (size_t)b * HVD + (size_t)g * 8)     = a;
            *(float4*)(out + (size_t)b * HVD + (size_t)g * 8 + 4) = c;
        }
    }
}

extern "C" void kernel_launch(void* const* d_in, const int* in_sizes, int n_in,
                              void* d_out, int out_size, void* d_ws, size_t ws_size,
                              hipStream_t stream)
{
    const float* x    = (const float*)d_in[0];   // (256, 64)
    const float* base = (const float*)d_in[1];   // (64, 100, 10000)
    float*       out  = (float*)d_out;           // (256, 10000)
    ushort*      part = (ushort*)d_ws;           // bf16 partials

    dim3 grid(NHT, DSPLIT);
    encode_kernel<<<grid, TPB, 0, stream>>>(x, base, part);
    finish_kernel<<<BATCH, FTPB, 0, stream>>>(part, out);
}

// Round 3
// 372.277 us; speedup vs baseline: 1.0079x; 1.0079x over previous
//
#include <hip/hip_runtime.h>
#include <hip/hip_fp16.h>
#include <hip/hip_bf16.h>

#define BATCH   256
#define DIMS    64
#define LEVELS  100
#define HVD     10000
#define WH      32        // h-tile columns per block
#define NHT     313       // ceil(HVD/WH); tile 312 has 16 valid cols
#define DSPLIT  4
#define DPER    16
#define NBUF    3         // TRIPLE buffer: awaited chunk has 2 compute phases to land
#define TPB     256       // 4 waves
#define FTPB    1024      // finish: 16 waves -> 4 waves/SIMD of TLP
#define CHUNK_FLOATS (LEVELS * WH)            // 3200 floats = 12.8 KB
#define NSTG    13        // staging instrs per chunk (8 rows/instr; p=12 half-masked)

typedef unsigned int   uint;
typedef unsigned short ushort;
typedef unsigned char  uchar;

// d_ws layout: [0, 20.48 MB) bf16 partial [DSPLIT][BATCH][HVD]

static __device__ __forceinline__ ushort f2bf(float f) {
    __hip_bfloat16 h = __float2bfloat16(f);   // RNE
    return *reinterpret_cast<ushort*>(&h);
}

// ---------------------------------------------------------------------------
// Encode: block = (h-tile 32 cols, d-split of 16 dims) x ALL 256 batches.
// NEVER-DRAIN K-loop, now 3-DEEP: chunks dc+1 AND dc+2 stay in flight during
// compute of dc, so the s_waitcnt at iter dc targets loads issued TWO compute
// phases ago (HBM latency ~900 cy < 2 phases) -> the wait is a no-op in
// steady state; HBM duty ~100% without relying on cross-block TLP.
// Chunk = 100 rows x 32 floats = 12.8 KB, staged by 13 instrs of
// 8 rows/instr (srow = lane>>3, scol = (lane&7)*4; p=12 masks rows >= 100).
// Per wave, loads/chunk = 4 (wave 0) or 3 (waves 1-3).
// Steady-state wait: vmcnt(6) = 2 future chunks x 3 loads (wave 0 over-waits
// by design, safe); tail: vmcnt(3), then vmcnt(0) at the last chunk.
// The K-loop issues NO other vmcnt ops (params computed in the prologue and
// fully drained by the __syncthreads below), so the manual counts are exact.
// Each base byte fetched once, coalesced (8 x 128 B segments per instr).
//
// Params packed as SPLIT arrays to fit 3 buffers at 3 blocks/CU:
//   s_alpha fp16 [DPER][BATCH] (8 KB) + s_lo u8 [DPER][BATCH] (4 KB);
//   hi is derived in-loop: ohi = min(olo+128, 99*128)  (2 VALU).
// LDS = 38.4 KB chunks + 12 KB prm = 50.7 KB -> 3 blocks/CU.
// ---------------------------------------------------------------------------
__global__ __launch_bounds__(TPB, 3) void encode_kernel(
    const float* __restrict__ x,
    const float* __restrict__ base,
    ushort*     __restrict__ partial)      // bf16 [DSPLIT][BATCH][HVD]
{
    __shared__ float  s_buf[NBUF][CHUNK_FLOATS];   // 38.4 KB
    __shared__ ushort s_alpha[DPER][BATCH];        // 8 KB
    __shared__ uchar  s_lo[DPER][BATCH];           // 4 KB

    const int tid   = threadIdx.x;
    const int w     = tid >> 6;            // wave 0..3
    const int lane  = tid & 63;
    const int htile = blockIdx.x;
    const int split = blockIdx.y;
    const int h0    = htile * WH;
    const int d0    = split * DPER;
    const int wvalid = (HVD - h0) < WH ? (HVD - h0) : WH;

    // Fused param setup (b = tid, d = d0 + k). Drained by the __syncthreads
    // below, so these loads never pollute the K-loop's vmcnt bookkeeping.
    {
        const float4* xr = (const float4*)(x + (size_t)tid * DIMS + d0);
        const float4 x0 = xr[0];
        const float4 x1 = xr[1];
        const float4 x2 = xr[2];
        const float4 x3 = xr[3];
        const float xv[16] = { x0.x, x0.y, x0.z, x0.w, x1.x, x1.y, x1.z, x1.w,
                               x2.x, x2.y, x2.z, x2.w, x3.x, x3.y, x3.z, x3.w };
        #pragma unroll
        for (int k = 0; k < DPER; ++k) {
            float xn = fminf(fmaxf(xv[k] * (float)(LEVELS - 1), 0.0f),
                             (float)(LEVELS - 1));
            float fl = floorf(xn);
            int   lo = (int)fl;
            s_alpha[k][tid] = (ushort)__half_as_ushort(__float2half(xn - fl));
            s_lo[k][tid]    = (uchar)lo;
        }
    }
    __syncthreads();   // params visible; all counters drained

    const int srow = lane >> 3;            // staging: row within 8-row group
    const int scol = (lane & 7) * 4;       // staging: float col
    const float* srcdim = base + (size_t)d0 * LEVELS * HVD + h0;

    auto issue_chunk = [&](int dc, int bufidx) {
        const float* src = srcdim + (size_t)dc * LEVELS * HVD;
        float* dst = &s_buf[bufidx][0];
        for (int p = w; p < NSTG; p += 4) {          // wave0:4, waves1-3:3
            const int row = 8 * p + srow;
            const float* g = src + (size_t)row * HVD + scol;
            if (row < LEVELS && scol < wvalid) {     // lane mask; instr still issues
                __builtin_amdgcn_global_load_lds(
                    (const __attribute__((address_space(1))) uint*)g,
                    (__attribute__((address_space(3))) uint*)(dst + p * 8 * WH),
                    16, 0, 0);
            }
        }
    };

    issue_chunk(0, 0);
    issue_chunk(1, 1);
    issue_chunk(2, 2);

    const int sub   = lane >> 4;           // batch sub 0..3
    const int p2    = lane & 15;           // col pair (2 floats) within 32 cols
    const int pb    = p2 * 8;              // byte offset within a 128 B row
    const int bbase = w * 64;              // this wave's 64 batches

    float2 acc[16];
    #pragma unroll
    for (int j = 0; j < 16; ++j) acc[j] = make_float2(0.f, 0.f);

    int cur = 0;                           // buffer holding chunk dc
    #pragma unroll 1
    for (int dc = 0; dc < DPER; ++dc) {
        // Wait for chunk dc only; chunks dc+1, dc+2 remain in flight.
        if (dc < DPER - 2)       asm volatile("s_waitcnt vmcnt(6)" ::: "memory");
        else if (dc == DPER - 2) asm volatile("s_waitcnt vmcnt(3)" ::: "memory");
        else                     asm volatile("s_waitcnt vmcnt(0)" ::: "memory");
        __builtin_amdgcn_s_barrier();      // all waves' chunk-dc portions landed

        const char* buf = (const char*)&s_buf[cur][0];
        #pragma unroll
        for (int j = 0; j < 16; ++j) {
            // broadcast reads of 4 consecutive batches' params; static select
            const uint2 av = *(const uint2*)&s_alpha[dc][bbase + 4 * j];
            const uint  lv = *(const uint*)&s_lo[dc][bbase + 4 * j];
            const uint  aw = (sub & 2) ? av.y : av.x;
            const float a  = __half2float(__ushort_as_half(
                                (ushort)((sub & 1) ? (aw >> 16) : (aw & 0xffffu))));
            const int olo = (int)((lv >> (8 * sub)) & 0xffu) << 7;  // lo * 128 B
            const int ohi = min(olo + 128, (LEVELS - 1) << 7);      // hi * 128 B
            const float2 vlo = *(const float2*)(buf + olo + pb);
            const float2 vhi = *(const float2*)(buf + ohi + pb);
            const float wl = 1.0f - a;
            acc[j].x += wl * vlo.x + a * vhi.x;
            acc[j].y += wl * vlo.y + a * vhi.y;
        }
        asm volatile("" ::: "memory");     // pin reads before the reuse barrier
        __builtin_amdgcn_s_barrier();      // all waves done reading buf[cur]
        if (dc + NBUF < DPER) issue_chunk(dc + NBUF, cur);  // refill freed buffer
        cur = (cur == NBUF - 1) ? 0 : cur + 1;
    }

    // bf16 partial store: per 16-lane group, one batch row x 64 B contiguous.
    if (p2 * 2 < wvalid) {
        #pragma unroll
        for (int j = 0; j < 16; ++j) {
            const int b = bbase + 4 * j + sub;
            const uint pk = (uint)f2bf(acc[j].x) | ((uint)f2bf(acc[j].y) << 16);
            *(uint*)(partial + ((size_t)split * BATCH + b) * (size_t)HVD + h0 + p2 * 2) = pk;
        }
    }
}

// ---------------------------------------------------------------------------
// Finish: SINGLE-PASS. Per batch row: sum the 4 bf16 partials into registers
// (<=16 floats/thread), block-reduce sum-of-squares, scale in-register,
// store out exactly once. 16 B uint4 loads: 8 bf16 per load per sp-stream.
// Partials are L3-resident (written ~40 us earlier) -> reads are cheap.
// ---------------------------------------------------------------------------
__global__ __launch_bounds__(FTPB) void finish_kernel(
    const ushort* __restrict__ partial,    // bf16 [DSPLIT][BATCH][HVD]
    float* __restrict__ out)               // fp32 [BATCH][HVD]
{
    const int b   = blockIdx.x;
    const int tid = threadIdx.x;

    // HVD/8 = 1250 groups of 8 floats; k=0: g=tid, k=1: g=tid+1024 (<1250)
    float4 v0[2], v1[2];
    float  ss = 0.f;
    #pragma unroll
    for (int k = 0; k < 2; ++k) {
        const int g = k * FTPB + tid;
        float4 a = make_float4(0.f, 0.f, 0.f, 0.f);
        float4 c = make_float4(0.f, 0.f, 0.f, 0.f);
        if (g < HVD / 8) {
            #pragma unroll
            for (int sp = 0; sp < DSPLIT; ++sp) {
                const uint4 u = *(const uint4*)(partial +
                    ((size_t)sp * BATCH + b) * (size_t)HVD + (size_t)g * 8);
                a.x += __uint_as_float(u.x << 16);
                a.y += __uint_as_float(u.x & 0xffff0000u);
                a.z += __uint_as_float(u.y << 16);
                a.w += __uint_as_float(u.y & 0xffff0000u);
                c.x += __uint_as_float(u.z << 16);
                c.y += __uint_as_float(u.z & 0xffff0000u);
                c.z += __uint_as_float(u.w << 16);
                c.w += __uint_as_float(u.w & 0xffff0000u);
            }
            ss += a.x * a.x + a.y * a.y + a.z * a.z + a.w * a.w
                + c.x * c.x + c.y * c.y + c.z * c.z + c.w * c.w;
        }
        v0[k] = a; v1[k] = c;
    }

    __shared__ float red[FTPB];
    red[tid] = ss;
    __syncthreads();
    #pragma unroll
    for (int sh = FTPB / 2; sh > 0; sh >>= 1) {
        if (tid < sh) red[tid] += red[tid + sh];
        __syncthreads();
    }
    const float inv = rsqrtf(red[0]);

    #pragma unroll
    for (int k = 0; k < 2; ++k) {
        const int g = k * FTPB + tid;
        if (g < HVD / 8) {
            float4 a = v0[k], c = v1[k];
            a.x *= inv; a.y *= inv; a.z *= inv; a.w *= inv;
            c.x *= inv; c.y *= inv; c.z *= inv; c.w *= inv;
            *(float4*)(out + (size_t)b * HVD + (size_t)g * 8)     = a;
            *(float4*)(out + (size_t)b * HVD + (size_t)g * 8 + 4) = c;
        }
    }
}

extern "C" void kernel_launch(void* const* d_in, const int* in_sizes, int n_in,
                              void* d_out, int out_size, void* d_ws, size_t ws_size,
                              hipStream_t stream)
{
    const float* x    = (const float*)d_in[0];   // (256, 64)
    const float* base = (const float*)d_in[1];   // (64, 100, 10000)
    float*       out  = (float*)d_out;           // (256, 10000)
    ushort*      part = (ushort*)d_ws;           // bf16 partials

    dim3 grid(NHT, DSPLIT);
    encode_kernel<<<grid, TPB, 0, stream>>>(x, base, part);
    finish_kernel<<<BATCH, FTPB, 0, stream>>>(part, out);
}

// Round 4
// 371.553 us; speedup vs baseline: 1.0099x; 1.0019x over previous
//
#include <hip/hip_runtime.h>
#include <hip/hip_fp16.h>
#include <hip/hip_bf16.h>

#define BATCH   256
#define DIMS    64
#define LEVELS  100
#define HVD     10000
#define WH      32        // h-tile columns per block
#define NHT     313       // ceil(HVD/WH); tile 312 has 16 valid cols
#define DSPLIT  4
#define DPER    16
#define NBUF    3         // TRIPLE buffer: awaited chunk has 2 compute phases to land
#define TPB     256       // 4 waves
#define FTPB    1024      // finish: 16 waves -> 4 waves/SIMD of TLP
#define CHUNK_FLOATS (LEVELS * WH)            // 3200 floats = 12.8 KB
#define NSTG    13        // staging instrs per chunk (8 rows/instr; p=12 half-masked)

typedef unsigned int   uint;
typedef unsigned short ushort;
typedef unsigned char  uchar;

// d_ws layout: [0, 20.48 MB) bf16 partial [DSPLIT][BATCH][HVD]

static __device__ __forceinline__ ushort f2bf(float f) {
    __hip_bfloat16 h = __float2bfloat16(f);   // RNE
    return *reinterpret_cast<ushort*>(&h);
}

// ---------------------------------------------------------------------------
// Encode: block = (h-tile 32 cols, d-split of 16 dims) x ALL 256 batches.
// NEVER-DRAIN K-loop, 3-deep, ONE barrier per iteration:
//   wait vmcnt(own chunk dc) -> s_barrier -> issue chunk dc+2 (into the
//   buffer freed by compute dc-1) -> compute dc -> s_waitcnt lgkmcnt(0).
// Safety: the iter-dc barrier proves every wave finished compute dc-1 AND
// its lgkmcnt(0) (reads complete, not just issued), so the refill of
// buf[(dc+2)%3] == buf[(dc-1)%3] cannot race any reader. Chunk-dc
// visibility: each wave drains its own portion (vmcnt) BEFORE the barrier.
// Per wave, loads/chunk = 4 (wave 0: p=0,4,8,12) or 3 (waves 1-3), so the
// steady-state wait is vmcnt(4) for wave 0 and vmcnt(3) for waves 1-3
// (exactly one future chunk in flight at the wait, two after the issue);
// last iter waits vmcnt(0). The K-loop consumes no VMEM register results,
// so the compiler inserts no vmcnt waits of its own inside the loop; the
// only compiler-inserted drain sits in the PROLOGUE (before the first x
// use), where it merely overlaps x latency with chunk 0/1 latency.
// Each base byte fetched once, coalesced (8 x 128 B segments per instr).
//
// Params (intra-wave only: wave w reads s_alpha/s_lo[ ][w*64 .. w*64+63],
// written by its own lanes) -> no block barrier, just lgkmcnt(0).
//   s_alpha fp16 [DPER][BATCH] (8 KB) + s_lo u8 [DPER][BATCH] (4 KB);
//   hi derived in-loop: ohi = min(olo+128, 99*128).
// LDS = 38.4 KB chunks + 12 KB prm = 50.7 KB -> 3 blocks/CU.
// ---------------------------------------------------------------------------
__global__ __launch_bounds__(TPB, 3) void encode_kernel(
    const float* __restrict__ x,
    const float* __restrict__ base,
    ushort*     __restrict__ partial)      // bf16 [DSPLIT][BATCH][HVD]
{
    __shared__ float  s_buf[NBUF][CHUNK_FLOATS];   // 38.4 KB
    __shared__ ushort s_alpha[DPER][BATCH];        // 8 KB
    __shared__ uchar  s_lo[DPER][BATCH];           // 4 KB

    const int tid   = threadIdx.x;
    const int w     = tid >> 6;            // wave 0..3
    const int lane  = tid & 63;
    const int htile = blockIdx.x;
    const int split = blockIdx.y;
    const int h0    = htile * WH;
    const int d0    = split * DPER;
    const int wvalid = (HVD - h0) < WH ? (HVD - h0) : WH;

    const int srow = lane >> 3;            // staging: row within 8-row group
    const int scol = (lane & 7) * 4;       // staging: float col
    const float* srcdim = base + (size_t)d0 * LEVELS * HVD + h0;

    auto issue_chunk = [&](int dc, int bufidx) {
        const float* src = srcdim + (size_t)dc * LEVELS * HVD;
        float* dst = &s_buf[bufidx][0];
        for (int p = w; p < NSTG; p += 4) {          // wave0:4, waves1-3:3
            const int row = 8 * p + srow;
            const float* g = src + (size_t)row * HVD + scol;
            if (row < LEVELS && scol < wvalid) {     // lane mask; instr still issues
                __builtin_amdgcn_global_load_lds(
                    (const __attribute__((address_space(1))) uint*)g,
                    (__attribute__((address_space(3))) uint*)(dst + p * 8 * WH),
                    16, 0, 0);
            }
        }
    };

    // PROLOGUE: x-loads first, then chunks 0-1, then params. sched_barrier
    // pins the issue order so the compiler's x-wait lands after the chunk
    // issues (overlapping their latencies).
    const float4* xr = (const float4*)(x + (size_t)tid * DIMS + d0);
    const float4 x0 = xr[0];
    const float4 x1 = xr[1];
    const float4 x2 = xr[2];
    const float4 x3 = xr[3];
    __builtin_amdgcn_sched_barrier(0);

    issue_chunk(0, 0);
    issue_chunk(1, 1);
    __builtin_amdgcn_sched_barrier(0);

    {
        const float xv[16] = { x0.x, x0.y, x0.z, x0.w, x1.x, x1.y, x1.z, x1.w,
                               x2.x, x2.y, x2.z, x2.w, x3.x, x3.y, x3.z, x3.w };
        #pragma unroll
        for (int k = 0; k < DPER; ++k) {
            float xn = fminf(fmaxf(xv[k] * (float)(LEVELS - 1), 0.0f),
                             (float)(LEVELS - 1));
            float fl = floorf(xn);
            s_alpha[k][tid] = (ushort)__half_as_ushort(__float2half(xn - fl));
            s_lo[k][tid]    = (uchar)(int)fl;
        }
    }
    asm volatile("s_waitcnt lgkmcnt(0)" ::: "memory");  // own-wave params visible
    __builtin_amdgcn_sched_barrier(0);

    const int sub   = lane >> 4;           // batch sub 0..3
    const int p2    = lane & 15;           // col pair (2 floats) within 32 cols
    const int pb    = p2 * 8;              // byte offset within a 128 B row
    const int bbase = w * 64;              // this wave's 64 batches

    float2 acc[16];
    #pragma unroll
    for (int j = 0; j < 16; ++j) acc[j] = make_float2(0.f, 0.f);

    int cur = 0;                           // buffer holding chunk dc
    #pragma unroll 1
    for (int dc = 0; dc < DPER; ++dc) {
        // Wait for chunk dc only (exact per-wave count); dc+1 stays in flight.
        if (dc < DPER - 1) {
            if (w == 0) asm volatile("s_waitcnt vmcnt(4)" ::: "memory");
            else        asm volatile("s_waitcnt vmcnt(3)" ::: "memory");
        } else {
            asm volatile("s_waitcnt vmcnt(0)" ::: "memory");
        }
        __builtin_amdgcn_s_barrier();      // all waves' chunk-dc portions landed
                                           // AND all compute dc-1 reads done

        if (dc + 2 < DPER) {               // refill buffer freed by compute dc-1
            int tgt = cur + 2; if (tgt >= NBUF) tgt -= NBUF;
            issue_chunk(dc + 2, tgt);
        }

        const char* buf = (const char*)&s_buf[cur][0];
        #pragma unroll
        for (int j = 0; j < 16; ++j) {
            // broadcast reads of 4 consecutive batches' params; static select
            const uint2 av = *(const uint2*)&s_alpha[dc][bbase + 4 * j];
            const uint  lv = *(const uint*)&s_lo[dc][bbase + 4 * j];
            const uint  aw = (sub & 2) ? av.y : av.x;
            const float a  = __half2float(__ushort_as_half(
                                (ushort)((sub & 1) ? (aw >> 16) : (aw & 0xffffu))));
            const int olo = (int)((lv >> (8 * sub)) & 0xffu) << 7;  // lo * 128 B
            const int ohi = min(olo + 128, (LEVELS - 1) << 7);      // hi * 128 B
            const float2 vlo = *(const float2*)(buf + olo + pb);
            const float2 vhi = *(const float2*)(buf + ohi + pb);
            const float wl = 1.0f - a;
            acc[j].x += wl * vlo.x + a * vhi.x;
            acc[j].y += wl * vlo.y + a * vhi.y;
        }
        asm volatile("s_waitcnt lgkmcnt(0)" ::: "memory");  // reads COMPLETE
        cur = (cur == NBUF - 1) ? 0 : cur + 1;              // before next barrier
    }

    // bf16 partial store: per 16-lane group, one batch row x 64 B contiguous.
    if (p2 * 2 < wvalid) {
        #pragma unroll
        for (int j = 0; j < 16; ++j) {
            const int b = bbase + 4 * j + sub;
            const uint pk = (uint)f2bf(acc[j].x) | ((uint)f2bf(acc[j].y) << 16);
            *(uint*)(partial + ((size_t)split * BATCH + b) * (size_t)HVD + h0 + p2 * 2) = pk;
        }
    }
}

// ---------------------------------------------------------------------------
// Finish: SINGLE-PASS. Per batch row: sum the 4 bf16 partials into registers
// (<=16 floats/thread), shuffle-reduce sum-of-squares (2 barriers total,
// was 11), scale in-register, store out exactly once.
// Partials are L3-resident (written ~40 us earlier) -> reads are cheap.
// ---------------------------------------------------------------------------
__global__ __launch_bounds__(FTPB) void finish_kernel(
    const ushort* __restrict__ partial,    // bf16 [DSPLIT][BATCH][HVD]
    float* __restrict__ out)               // fp32 [BATCH][HVD]
{
    const int b    = blockIdx.x;
    const int tid  = threadIdx.x;
    const int wid  = tid >> 6;
    const int lane = tid & 63;

    // HVD/8 = 1250 groups of 8 floats; k=0: g=tid, k=1: g=tid+1024 (<1250)
    float4 v0[2], v1[2];
    float  ss = 0.f;
    #pragma unroll
    for (int k = 0; k < 2; ++k) {
        const int g = k * FTPB + tid;
        float4 a = make_float4(0.f, 0.f, 0.f, 0.f);
        float4 c = make_float4(0.f, 0.f, 0.f, 0.f);
        if (g < HVD / 8) {
            #pragma unroll
            for (int sp = 0; sp < DSPLIT; ++sp) {
                const uint4 u = *(const uint4*)(partial +
                    ((size_t)sp * BATCH + b) * (size_t)HVD + (size_t)g * 8);
                a.x += __uint_as_float(u.x << 16);
                a.y += __uint_as_float(u.x & 0xffff0000u);
                a.z += __uint_as_float(u.y << 16);
                a.w += __uint_as_float(u.y & 0xffff0000u);
                c.x += __uint_as_float(u.z << 16);
                c.y += __uint_as_float(u.z & 0xffff0000u);
                c.z += __uint_as_float(u.w << 16);
                c.w += __uint_as_float(u.w & 0xffff0000u);
            }
            ss += a.x * a.x + a.y * a.y + a.z * a.z + a.w * a.w
                + c.x * c.x + c.y * c.y + c.z * c.z + c.w * c.w;
        }
        v0[k] = a; v1[k] = c;
    }

    // wave-level shuffle reduce (no barriers), then 16 wave sums via LDS
    #pragma unroll
    for (int off = 32; off > 0; off >>= 1) ss += __shfl_down(ss, off, 64);

    __shared__ float red[FTPB / 64];
    if (lane == 0) red[wid] = ss;
    __syncthreads();
    if (wid == 0) {
        float v = (lane < FTPB / 64) ? red[lane] : 0.f;
        #pragma unroll
        for (int off = 8; off > 0; off >>= 1) v += __shfl_down(v, off, 64);
        if (lane == 0) red[0] = v;
    }
    __syncthreads();
    const float inv = rsqrtf(red[0]);

    #pragma unroll
    for (int k = 0; k < 2; ++k) {
        const int g = k * FTPB + tid;
        if (g < HVD / 8) {
            float4 a = v0[k], c = v1[k];
            a.x *= inv; a.y *= inv; a.z *= inv; a.w *= inv;
            c.x *= inv; c.y *= inv; c.z *= inv; c.w *= inv;
            *(float4*)(out + (size_t)b * HVD + (size_t)g * 8)     = a;
            *(float4*)(out + (size_t)b * HVD + (size_t)g * 8 + 4) = c;
        }
    }
}

extern "C" void kernel_launch(void* const* d_in, const int* in_sizes, int n_in,
                              void* d_out, int out_size, void* d_ws, size_t ws_size,
                              hipStream_t stream)
{
    const float* x    = (const float*)d_in[0];   // (256, 64)
    const float* base = (const float*)d_in[1];   // (64, 100, 10000)
    float*       out  = (float*)d_out;           // (256, 10000)
    ushort*      part = (ushort*)d_ws;           // bf16 partials

    dim3 grid(NHT, DSPLIT);
    encode_kernel<<<grid, TPB, 0, stream>>>(x, base, part);
    finish_kernel<<<BATCH, FTPB, 0, stream>>>(part, out);
}